// Round 8
// baseline (25812.796 us; speedup 1.0000x reference)
//
#include <hip/hip_runtime.h>

// ---------------------------------------------------------------------------
// Persistent 2-layer GRU + output Linear for MI355X (gfx950).
// B=32, T=1024, I=128, H=512, O=128.  ALL I/O FP32.
// R20: XCD-LOCAL RECURRENCE. Ledger: R14 hoist / R16 counters / R19 overlap
// all neutral-or-worse; R15 flag-padding +12%. Residual 5.5us/round = agent
// (MALL) hop chain. Fix: each layer = 32 WGs x 16 cols on ONE XCD (role =
// w%8: 0->L0, 1->L1, 2->OUT(cb<2), else exit). Local ring = plain write-
// through stores (land in XCD-shared L2) + vmcnt drain + sc0 flag; consumer
// polls sc0 (L2 RT ~0.15us vs MALL ~1us), data = plain loads (write-once).
// Placement verified in-kernel (HW_REG_XCC_ID; composite check: per-layer
// all-equal AND L0!=L1 AND in-range) -> else SAFE mode (agent everywhere,
// == R15 semantics). Mirror agent flags + every-64th-poll fallback make a
// broken-sc0 world slow, never wrong. Cross-XCD edges (L0->L1 y0, L1->OUT
// y1) ride remote agent rings published by WAVE1 with ONE-ROUND-LAGGED
// flags: drain of round i's remote stores happens at round i+1 (free by
// then) -> MALL RT never on the critical cycle; consumers absorb it as a
// constant pipeline lag (no backpressure, full-sequence rings).
// 16-col WGs: 3 full B-tiles (r,z,n) - no wasted rows; hi weights in LDS,
// lo weights in registers (R17-proven numerics); ex has 4 groups (r,z,
// n_ih,n_hh). Slot fragment layout UNCHANGED (readers identical).
// Slot map: y0[idx]=h0[t=idx-1] (idx0=zeros); y1[idx]=h1[t=idx-1].
// Round i: L0 reads y0[i] hh (local flags>=i), writes y0[i+1]+y0r[i+1],
//   local flag i+1, remote flag i (lagged). L1 reads y0r[i] (remote>=i) +
//   y1[i-1] (local>=i), writes y1[i]+y1r[i]. OUT reads y1r[i-1] (remote>=i).
// ---------------------------------------------------------------------------

typedef __attribute__((ext_vector_type(8))) short short8;
typedef __attribute__((ext_vector_type(4))) float floatx4;

#define MFMA_BF16(a, b, c) __builtin_amdgcn_mfma_f32_16x16x32_bf16(a, b, c, 0, 0, 0)

#define NWG 256
#define FSTR 16                  // flag stride in uints (64B between flags)
#define EX_REC 99072             // rec ex offset (after 48x1032x2B hi weights)
#define EX_OUT 66560             // out ex offset (after Wout)
#define HBUF_OFF 131840
#define LDS_BYTES 133888
#define HID_OFF 4194304
#define SLOT 32768               // ushorts per ring slot

// flag index bases (xFSTR): local, remote, xcc-table, mirror
#define FL_L0 0
#define FL_L1 64
#define FR_L0 128
#define FR_L1 192
#define FX 256
#define FM_L0 320
#define FM_L1 384

__device__ __align__(16) unsigned g_flags[8192];
__device__ __align__(16) unsigned short g_y0[33587200];   // local rings
__device__ __align__(16) unsigned short g_y1[33587200];
__device__ __align__(16) unsigned short g_y0r[33587200];  // remote rings
__device__ __align__(16) unsigned short g_y1r[33587200];
__device__ __align__(16) unsigned short g_xf[8388608];

static __device__ __forceinline__ float bf2f(unsigned short u) {
  unsigned v = ((unsigned)u) << 16;
  return __builtin_bit_cast(float, v);
}
static __device__ __forceinline__ unsigned short f2bf(float f) {
  unsigned u = __builtin_bit_cast(unsigned, f);
  u = (u + 0x7fffu + ((u >> 16) & 1u)) >> 16;  // RNE
  return (unsigned short)u;
}
static __device__ __forceinline__ float sigf(float x) {
  return 1.f / (1.f + __expf(-x));
}
static __device__ __forceinline__ void st8(unsigned short* p, unsigned long long v) {
  __hip_atomic_store((unsigned long long*)p, v, __ATOMIC_RELAXED,
                     __HIP_MEMORY_SCOPE_AGENT);
}
static __device__ __forceinline__ void st8_wg(unsigned short* p, unsigned long long v) {
  __hip_atomic_store((unsigned long long*)p, v, __ATOMIC_RELAXED,
                     __HIP_MEMORY_SCOPE_WORKGROUP);  // plain store, write-through to L2
}
static __device__ __forceinline__ unsigned long long pack4(const unsigned short* u) {
  return (unsigned long long)u[0] | ((unsigned long long)u[1] << 16) |
         ((unsigned long long)u[2] << 32) | ((unsigned long long)u[3] << 48);
}
static __device__ __forceinline__ unsigned ldagent(const unsigned* p) {
  return __hip_atomic_load(p, __ATOMIC_RELAXED, __HIP_MEMORY_SCOPE_AGENT);
}
static __device__ __forceinline__ void stagent(unsigned* p, unsigned v) {
  __hip_atomic_store(p, v, __ATOMIC_RELAXED, __HIP_MEMORY_SCOPE_AGENT);
}
// sc0 = L2-coherent (XCD-local) flag ops: load bypasses L1, reads shared L2
static __device__ __forceinline__ unsigned ldflag_sc0(const unsigned* p) {
  unsigned v;
  asm volatile("global_load_dword %0, %1, off sc0\n\ts_waitcnt vmcnt(0)"
               : "=v"(v) : "v"(p) : "memory");
  return v;
}
static __device__ __forceinline__ void stflag_sc0(unsigned* p, unsigned v) {
  asm volatile("global_store_dword %0, %1, off sc0" :: "v"(p), "v"(v) : "memory");
}
static __device__ __forceinline__ void ldfrag(const unsigned short* slot, int kb,
                                              int t, int lane, short8& hi,
                                              short8& lo) {
  const unsigned short* base = slot + (kb * 2 + t) * 1024 + lane * 8;
  hi = *(const short8*)base;
  lo = *(const short8*)(base + 512);
}

extern "C" __global__ void gru_init() {
  int i = blockIdx.x * blockDim.x + threadIdx.x;  // 73728 threads
  if (i < 8192) g_flags[i] = 0u;
  else if (i < 24576) ((unsigned*)g_y0)[i - 8192] = 0u;
  else if (i < 40960) ((unsigned*)g_y1)[i - 24576] = 0u;
  else if (i < 57344) ((unsigned*)g_y0r)[i - 40960] = 0u;
  else if (i < 73728) ((unsigned*)g_y1r)[i - 57344] = 0u;
}

extern "C" __global__ void x_arrange(const float* __restrict__ x) {
  int gid = blockIdx.x * 256 + threadIdx.x;  // 524288 total
  int t = gid >> 9;
  int rem = gid & 511;
  int kb = rem >> 7;
  int tile = (rem >> 6) & 1;
  int lane = rem & 63;
  int b = tile * 16 + (lane & 15);
  int k = kb * 32 + (lane >> 4) * 8;
  const float* src = x + b * 131072 + t * 128 + k;  // x is (B,T,I)
  short8 hi, lo;
#pragma unroll
  for (int e = 0; e < 8; ++e) {
    float v = src[e];
    unsigned short h = f2bf(v);
    hi[e] = (short)h;
    lo[e] = (short)f2bf(v - bf2f(h));
  }
  unsigned short* dst = g_xf + ((t * 4 + kb) * 2 + tile) * 1024;
  *(short8*)(dst + lane * 8) = hi;
  *(short8*)(dst + 512 + lane * 8) = lo;
}

// lo-weights -> registers, mirroring the k-loop B-fragment layout (3 tiles)
template <int LAYER, int KSW>
__device__ __forceinline__ void load_blo3(int q, int lane, int jb,
                                          const float* __restrict__ Wih,
                                          const float* __restrict__ Whh,
                                          short8 (*blo)[3]) {
  constexpr int IHK = LAYER ? 512 : 128;
  const int lm = lane & 15, lq = lane >> 4;
#pragma unroll
  for (int s = 0; s < KSW; ++s) {
    int ks = q * KSW + s;
    int colk = ks * 32 + lq * 8;
#pragma unroll
    for (int g = 0; g < 3; ++g) {
      int grow = g * 512 + jb + lm;
      const float* src = (colk < IHK) ? (Wih + grow * IHK + colk)
                                      : (Whh + grow * 512 + (colk - IHK));
      short8 lo8;
#pragma unroll
      for (int e = 0; e < 8; ++e) {
        float v = src[e];
        lo8[e] = (short)f2bf(v - bf2f(f2bf(v)));
      }
      blo[s][g] = lo8;
    }
  }
}

// ---- recurrent layer step: 16 h-cols, 3 B-tiles, hi(LDS)+lo(reg) ----
template <int LAYER>
__device__ __forceinline__ void layer_step16(
    int i, int tid, int q, int lane, int jb, int fastmode,
    const unsigned short* whi, const short8 (*blo)[3],
    const unsigned short* ihs, const unsigned short* hhs,
    unsigned short* slotL, unsigned short* slotR,
    unsigned* pfL, unsigned* pfM, unsigned* pfR, unsigned pubval,
    float* ex, float* hbuf, float* __restrict__ dout,
    const float* bsr, const float* bsz, const float* bnin, const float* bnhn,
    float* hp) {
  constexpr int IHK = LAYER ? 512 : 128;
  constexpr int IHS = IHK / 32;
  constexpr int KSW = LAYER ? 8 : 5;
  constexpr int WSTR = IHK + 512 + 8;
  const int lm = lane & 15, lq = lane >> 4;

  const floatx4 z4 = {0.f, 0.f, 0.f, 0.f};
  floatx4 rh[2] = {z4, z4}, rl[2] = {z4, z4};
  floatx4 zh[2] = {z4, z4}, zl[2] = {z4, z4};
  floatx4 nihh[2] = {z4, z4}, nihl[2] = {z4, z4};
  floatx4 nhhh[2] = {z4, z4}, nhhl[2] = {z4, z4};

#pragma unroll
  for (int s = 0; s < KSW; ++s) {
    int ks = q * KSW + s;
    int colk = ks * 32 + lq * 8;
    short8 ah[2], al[2];
    if (ks < IHS) {
      if (LAYER == 0) {  // fragment-layout x (precomputed)
        const unsigned short* xb = g_xf + (i * 4 + ks) * 2048;
        ah[0] = *(const short8*)(xb + lane * 8);
        al[0] = *(const short8*)(xb + 512 + lane * 8);
        ah[1] = *(const short8*)(xb + 1024 + lane * 8);
        al[1] = *(const short8*)(xb + 1536 + lane * 8);
      } else {
        ldfrag(ihs, ks, 0, lane, ah[0], al[0]);
        ldfrag(ihs, ks, 1, lane, ah[1], al[1]);
      }
    } else {
      ldfrag(hhs, ks - IHS, 0, lane, ah[0], al[0]);
      ldfrag(hhs, ks - IHS, 1, lane, ah[1], al[1]);
    }
    short8 bh0 = *(const short8*)(whi + (0 * 16 + lm) * WSTR + colk);
    short8 bh1 = *(const short8*)(whi + (1 * 16 + lm) * WSTR + colk);
    short8 bh2 = *(const short8*)(whi + (2 * 16 + lm) * WSTR + colk);
    short8 bl0 = blo[s][0], bl1 = blo[s][1], bl2 = blo[s][2];
#pragma unroll
    for (int t = 0; t < 2; ++t) {
      rh[t] = MFMA_BF16(ah[t], bh0, rh[t]);
      rl[t] = MFMA_BF16(ah[t], bl0, rl[t]);
      rl[t] = MFMA_BF16(al[t], bh0, rl[t]);
      zh[t] = MFMA_BF16(ah[t], bh1, zh[t]);
      zl[t] = MFMA_BF16(ah[t], bl1, zl[t]);
      zl[t] = MFMA_BF16(al[t], bh1, zl[t]);
      if (ks < IHS) {
        nihh[t] = MFMA_BF16(ah[t], bh2, nihh[t]);
        nihl[t] = MFMA_BF16(ah[t], bl2, nihl[t]);
        nihl[t] = MFMA_BF16(al[t], bh2, nihl[t]);
      } else {
        nhhh[t] = MFMA_BF16(ah[t], bh2, nhhh[t]);
        nhhl[t] = MFMA_BF16(ah[t], bl2, nhhl[t]);
        nhhl[t] = MFMA_BF16(al[t], bh2, nhhl[t]);
      }
    }
  }
#pragma unroll
  for (int t = 0; t < 2; ++t) {
    *(floatx4*)(ex + ((0 * 4 + q) * 2 + t) * 256 + lane * 4) = rh[t] + rl[t];
    *(floatx4*)(ex + ((1 * 4 + q) * 2 + t) * 256 + lane * 4) = zh[t] + zl[t];
    *(floatx4*)(ex + ((2 * 4 + q) * 2 + t) * 256 + lane * 4) = nihh[t] + nihl[t];
    *(floatx4*)(ex + ((3 * 4 + q) * 2 + t) * 256 + lane * 4) = nhhh[t] + nhhl[t];
  }
  __syncthreads();

  // elementwise: thread owns batch m = tid>>3 and cols j2, j2+8
  int m = tid >> 3, j2 = tid & 7;
  int quad = (m >> 2) & 3, reg = m & 3, mh = m >> 4;
#pragma unroll
  for (int jh = 0; jh < 2; ++jh) {
    int j = j2 + 8 * jh;
    int off = (quad * 16 + j) * 4 + reg;
    float sr = 0, sz = 0, sih = 0, shh = 0;
#pragma unroll
    for (int qq = 0; qq < 4; ++qq) {
      sr += ex[((0 * 4 + qq) * 2 + mh) * 256 + off];
      sz += ex[((1 * 4 + qq) * 2 + mh) * 256 + off];
      sih += ex[((2 * 4 + qq) * 2 + mh) * 256 + off];
      shh += ex[((3 * 4 + qq) * 2 + mh) * 256 + off];
    }
    float r = sigf(sr + bsr[jh]);
    float z = sigf(sz + bsz[jh]);
    float n = tanhf(sih + bnin[jh] + r * (shh + bnhn[jh]));
    float h = (1.f - z) * n + z * hp[jh];
    hp[jh] = h;
    hbuf[m * 16 + j] = h;
    if (i == (LAYER ? 1024 : 1023))
      dout[HID_OFF + LAYER * 16384 + m * 512 + jb + j] = h;
  }
  __syncthreads();

  if (tid < 64) {
    // ---- wave0: LOCAL ring publish (critical path; L2-scope in FAST) ----
    int b = tid & 31, ch = tid >> 5;
    int col0 = jb + 8 * ch;
    int kb = col0 >> 5, quadw = (col0 >> 3) & 3, tb = b >> 4;
    unsigned short h4[8], l4[8];
#pragma unroll
    for (int e = 0; e < 8; ++e) {
      float v = hbuf[b * 16 + ch * 8 + e];
      unsigned short hh16 = f2bf(v);
      h4[e] = hh16;
      l4[e] = f2bf(v - bf2f(hh16));
    }
    unsigned short* p = slotL + (kb * 2 + tb) * 1024 + ((b & 15) + 16 * quadw) * 8;
    if (fastmode) {
      st8_wg(p, pack4(h4)); st8_wg(p + 4, pack4(h4 + 4));
      st8_wg(p + 512, pack4(l4)); st8_wg(p + 516, pack4(l4 + 4));
    } else {
      st8(p, pack4(h4)); st8(p + 4, pack4(h4 + 4));
      st8(p + 512, pack4(l4)); st8(p + 516, pack4(l4 + 4));
    }
    asm volatile("s_waitcnt vmcnt(0)" ::: "memory");
    if (tid == 0) {
      if (fastmode) stflag_sc0(pfL, pubval);
      else stagent(pfL, pubval);
      stagent(pfM, pubval);  // agent mirror (fallback gate; data already drained)
    }
  } else if (tid < 128) {
    // ---- wave1: REMOTE ring, one-round-lagged publish (off critical path).
    // Drain waits LAST round's remote stores (long since complete), then the
    // lagged flag (value pubval-1 gates last round's slot), then issue this
    // round's remote stores WITHOUT waiting.
    asm volatile("s_waitcnt vmcnt(0)" ::: "memory");
    if (tid == 64) stagent(pfR, pubval - 1u);
    int mm = tid - 64;
    int b = mm & 31, ch = mm >> 5;
    int col0 = jb + 8 * ch;
    int kb = col0 >> 5, quadw = (col0 >> 3) & 3, tb = b >> 4;
    unsigned short h4[8], l4[8];
#pragma unroll
    for (int e = 0; e < 8; ++e) {
      float v = hbuf[b * 16 + ch * 8 + e];
      unsigned short hh16 = f2bf(v);
      h4[e] = hh16;
      l4[e] = f2bf(v - bf2f(hh16));
    }
    unsigned short* p = slotR + (kb * 2 + tb) * 1024 + ((b & 15) + 16 * quadw) * 8;
    st8(p, pack4(h4)); st8(p + 4, pack4(h4 + 4));
    st8(p + 512, pack4(l4)); st8(p + 516, pack4(l4 + 4));
  }
}

__device__ __forceinline__ void out_step(
    int i, int tid, int lane, int q, int ob,
    const unsigned short* wl, float* ex,
    float* __restrict__ dout, const float* bo) {
  const int lm = lane & 15, lq = lane >> 4;
  const unsigned short* slot = g_y1r + (size_t)(i - 1) * SLOT;  // y1[t=i-2]
  const floatx4 z4 = {0.f, 0.f, 0.f, 0.f};
  floatx4 acc[4][2];
#pragma unroll
  for (int nt = 0; nt < 4; ++nt) { acc[nt][0] = z4; acc[nt][1] = z4; }
#pragma unroll
  for (int s = 0; s < 4; ++s) {
    int ks = q * 4 + s;
    int colk = ks * 32 + lq * 8;
    short8 a0 = *(const short8*)(slot + (ks * 2 + 0) * 1024 + lane * 8);
    short8 a1 = *(const short8*)(slot + (ks * 2 + 1) * 1024 + lane * 8);
#pragma unroll
    for (int nt = 0; nt < 4; ++nt) {
      short8 b = *(const short8*)(wl + (nt * 16 + lm) * 520 + colk);
      acc[nt][0] = MFMA_BF16(a0, b, acc[nt][0]);
      acc[nt][1] = MFMA_BF16(a1, b, acc[nt][1]);
    }
  }
#pragma unroll
  for (int nt = 0; nt < 4; ++nt) {
    *(floatx4*)(ex + ((q * 4 + nt) * 2 + 0) * 256 + lane * 4) = acc[nt][0];
    *(floatx4*)(ex + ((q * 4 + nt) * 2 + 1) * 256 + lane * 4) = acc[nt][1];
  }
  __syncthreads();
  int m = tid >> 3, oc = (tid & 7) * 8;
  int t_out = i - 2;
  float sv[8];
#pragma unroll
  for (int k = 0; k < 8; ++k) {
    int o = oc + k;
    int nt = o >> 4, jj = o & 15;
    int off = (((m >> 2) & 3) * 16 + jj) * 4 + (m & 3);
    int mh = m >> 4;
    float s = bo[k];
#pragma unroll
    for (int qq = 0; qq < 4; ++qq) s += ex[((qq * 4 + nt) * 2 + mh) * 256 + off];
    sv[k] = s;
  }
  float* dst = dout + m * 131072 + t_out * 128 + ob + oc;
  *(floatx4*)dst = floatx4{sv[0], sv[1], sv[2], sv[3]};
  *(floatx4*)(dst + 4) = floatx4{sv[4], sv[5], sv[6], sv[7]};
}

extern "C" __global__ void __launch_bounds__(256, 1) gru_main(
    const float* __restrict__ Wih0, const float* __restrict__ Whh0,
    const float* __restrict__ bih0, const float* __restrict__ bhh0,
    const float* __restrict__ Wih1, const float* __restrict__ Whh1,
    const float* __restrict__ bih1, const float* __restrict__ bhh1,
    const float* __restrict__ Wout, const float* __restrict__ boutp,
    float* __restrict__ dout) {
  extern __shared__ char smem[];
  __shared__ int sbail;
  __shared__ int smode;

  const int w = blockIdx.x;
  const int tid = threadIdx.x;
  const int lane = tid & 63;
  const int q = tid >> 6;
  const int xcd = w & 7;
  const int cb = w >> 3;
  int role;
  if (xcd == 0) role = 0;
  else if (xcd == 1) role = 1;
  else if (xcd == 2 && cb < 2) role = 2;
  else return;

  if (tid == 0) { sbail = 0; smode = 0; }

  // xcc report (early, overlaps weight loading)
  if (role < 2 && tid == 0) {
    unsigned x = __builtin_amdgcn_s_getreg(6164) & 0xFu;  // HW_REG_XCC_ID[3:0]
    stagent(&g_flags[(FX + (role ? 32 : 0) + cb) * FSTR], 1u + x);
  }

  unsigned short* whi = (unsigned short*)smem;
  float* ex = (float*)(smem + (role == 2 ? EX_OUT : EX_REC));
  float* hbuf = (float*)(smem + HBUF_OFF);
  for (int idx = tid; idx < 8192; idx += 256) ex[idx] = 0.f;

  float bsr[2] = {0, 0}, bsz[2] = {0, 0}, bnin[2] = {0, 0}, bnhn[2] = {0, 0};
  float bo[8] = {0, 0, 0, 0, 0, 0, 0, 0};
  int jb = 0, ob = 0;
  short8 blo[8][3];

  if (role < 2) {
    jb = cb * 16;
    const int IHK = role ? 512 : 128;
    const int KTOT = IHK + 512;
    const int WSTR = KTOT + 8;
    const float* Wih = role ? Wih1 : Wih0;
    const float* Whh = role ? Whh1 : Whh0;
    const float* bih = role ? bih1 : bih0;
    const float* bhh = role ? bhh1 : bhh0;
    int cpr = KTOT / 8;
    for (int idx = tid; idx < 48 * cpr; idx += 256) {
      int r = idx / cpr, c = idx - r * cpr;
      int k0 = c * 8;
      int g = r >> 4, ccol = r & 15;
      int grow = g * 512 + jb + ccol;
      const float* src = (k0 < IHK) ? (Wih + grow * IHK + k0)
                                    : (Whh + grow * 512 + (k0 - IHK));
      short8 hi8;
#pragma unroll
      for (int e = 0; e < 8; ++e) hi8[e] = (short)f2bf(src[e]);
      *(short8*)(whi + r * WSTR + k0) = hi8;
    }
    for (int idx = tid; idx < 48 * 8; idx += 256)
      whi[(idx >> 3) * WSTR + KTOT + (idx & 7)] = 0;
    if (role == 0) load_blo3<0, 5>(q, lane, jb, Wih0, Whh0, blo);
    else load_blo3<1, 8>(q, lane, jb, Wih1, Whh1, blo);
    int j2 = tid & 7;
#pragma unroll
    for (int jh = 0; jh < 2; ++jh) {
      int g0 = jb + j2 + 8 * jh;
      bsr[jh] = bih[g0] + bhh[g0];
      bsz[jh] = bih[512 + g0] + bhh[512 + g0];
      bnin[jh] = bih[1024 + g0];
      bnhn[jh] = bhh[1024 + g0];
    }
  } else {
    ob = cb * 64;
    unsigned short* wout_l = (unsigned short*)smem;
    for (int idx = tid; idx < 64 * 64; idx += 256) {
      int r = idx >> 6, c = idx & 63;
      const float* src = Wout + (ob + r) * 512 + c * 8;
      short8 hi8;
#pragma unroll
      for (int e = 0; e < 8; ++e) hi8[e] = (short)f2bf(src[e]);
      *(short8*)(wout_l + r * 520 + c * 8) = hi8;
    }
    for (int idx = tid; idx < 64 * 8; idx += 256)
      wout_l[(idx >> 3) * 520 + 512 + (idx & 7)] = 0;
#pragma unroll
    for (int k = 0; k < 8; ++k) bo[k] = boutp[ob + (tid & 7) * 8 + k];
  }

  // xcc sweep -> FAST/SAFE decision (composite, garbage-proof)
  if (role < 2 && tid < 64) {
    unsigned v = 0;
    int guard = 0;
    for (;;) {
      v = ldagent(&g_flags[(FX + lane) * FSTR]);
      if (__ballot(v != 0u) == ~0ull) break;
      __builtin_amdgcn_s_sleep(1);
      if (++guard > (1 << 17)) break;
    }
    unsigned v0 = __shfl(v, 0), v32 = __shfl(v, 32);
    bool eq = __ballot((lane < 32) ? (v == v0) : (v == v32)) == ~0ull;
    bool inr = __ballot(v >= 1u && v <= 8u) == ~0ull;
    if (tid == 0) smode = (eq && inr && v0 != v32) ? 1 : 0;
  }
  // one-time tag invalidate: clears prior-launch ring lines from L1/L2
  __builtin_amdgcn_fence(__ATOMIC_ACQUIRE, "agent");
  __syncthreads();
  const int fastmode = (role < 2) ? smode : 0;

  unsigned* pfL = (role < 2) ? &g_flags[((role ? FL_L1 : FL_L0) + cb) * FSTR] : nullptr;
  unsigned* pfM = (role < 2) ? &g_flags[((role ? FM_L1 : FM_L0) + cb) * FSTR] : nullptr;
  unsigned* pfR = (role < 2) ? &g_flags[((role ? FR_L1 : FR_L0) + cb) * FSTR] : nullptr;

  float hp[2] = {0.f, 0.f};

  for (int i = 0; i < 1026; ++i) {
    // ---- single-wave poll (R15 shape); sc0 local polls in FAST mode with
    // every-64th agent-mirror fallback; remote gates always agent ----
    if (i > 0 && tid < 64) {
      const unsigned tgt = (unsigned)i;
      int guard = 0;
      for (;;) {
        bool ok = true;
        if (role == 0) {
          if (lane < 32) {
            unsigned v;
            if (fastmode) {
              v = ldflag_sc0(&g_flags[(FL_L0 + lane) * FSTR]);
              if ((guard & 63) == 63) {
                unsigned vm = ldagent(&g_flags[(FM_L0 + lane) * FSTR]);
                if (vm > v) v = vm;
              }
            } else {
              v = ldagent(&g_flags[(FL_L0 + lane) * FSTR]);
            }
            ok = v >= tgt;
          }
        } else if (role == 1) {
          if (lane < 32) {
            unsigned v;
            if (fastmode) {
              v = ldflag_sc0(&g_flags[(FL_L1 + lane) * FSTR]);
              if ((guard & 63) == 63) {
                unsigned vm = ldagent(&g_flags[(FM_L1 + lane) * FSTR]);
                if (vm > v) v = vm;
              }
            } else {
              v = ldagent(&g_flags[(FL_L1 + lane) * FSTR]);
            }
            ok = v >= tgt;
          } else {
            ok = ldagent(&g_flags[(FR_L0 + (lane - 32)) * FSTR]) >= tgt;
          }
        } else {
          if (lane < 32)
            ok = ldagent(&g_flags[(FR_L1 + lane) * FSTR]) >= tgt;
        }
        if (__ballot(ok) == ~0ull) break;
        __builtin_amdgcn_s_sleep(1);
        if (++guard > (1 << 17)) { sbail = 1; break; }
      }
      asm volatile("" ::: "memory");
    }
    __syncthreads();
    if (sbail) break;

    bool active = (role == 0) ? (i < 1024)
                : (role == 1) ? (i >= 1 && i < 1025)
                              : (i >= 2);
    if (role == 0) {
      if (active) {
        layer_step16<0>(i, tid, q, lane, jb, fastmode, whi, blo,
                        nullptr, g_y0 + (size_t)i * SLOT,
                        g_y0 + (size_t)(i + 1) * SLOT,
                        g_y0r + (size_t)(i + 1) * SLOT,
                        pfL, pfM, pfR, (unsigned)(i + 1),
                        ex, hbuf, dout, bsr, bsz, bnin, bnhn, hp);
      } else {
        if (tid == 0) {
          if (fastmode) stflag_sc0(pfL, (unsigned)(i + 1));
          else stagent(pfL, (unsigned)(i + 1));
          stagent(pfM, (unsigned)(i + 1));
        }
        if (tid == 64) {
          asm volatile("s_waitcnt vmcnt(0)" ::: "memory");
          stagent(pfR, (unsigned)i);
        }
      }
    } else if (role == 1) {
      if (active) {
        layer_step16<1>(i, tid, q, lane, jb, fastmode, whi, blo,
                        g_y0r + (size_t)i * SLOT, g_y1 + (size_t)(i - 1) * SLOT,
                        g_y1 + (size_t)i * SLOT, g_y1r + (size_t)i * SLOT,
                        pfL, pfM, pfR, (unsigned)(i + 1),
                        ex, hbuf, dout, bsr, bsz, bnin, bnhn, hp);
      } else {
        if (tid == 0) {
          if (fastmode) stflag_sc0(pfL, (unsigned)(i + 1));
          else stagent(pfL, (unsigned)(i + 1));
          stagent(pfM, (unsigned)(i + 1));
        }
        if (tid == 64) {
          asm volatile("s_waitcnt vmcnt(0)" ::: "memory");
          stagent(pfR, (unsigned)i);
        }
      }
    } else if (active) {
      out_step(i, tid, lane, q, ob, (const unsigned short*)smem, ex, dout, bo);
    }
    __syncthreads();
  }
}

extern "C" void kernel_launch(void* const* d_in, const int* in_sizes, int n_in,
                              void* d_out, int out_size, void* d_ws, size_t ws_size,
                              hipStream_t stream) {
  const float* x = (const float*)d_in[0];
  const float* Wih0 = (const float*)d_in[1];
  const float* Whh0 = (const float*)d_in[2];
  const float* bih0 = (const float*)d_in[3];
  const float* bhh0 = (const float*)d_in[4];
  const float* Wih1 = (const float*)d_in[5];
  const float* Whh1 = (const float*)d_in[6];
  const float* bih1 = (const float*)d_in[7];
  const float* bhh1 = (const float*)d_in[8];
  const float* Wout = (const float*)d_in[9];
  const float* bout = (const float*)d_in[10];

  hipLaunchKernelGGL(gru_init, dim3(288), dim3(256), 0, stream);
  hipLaunchKernelGGL(x_arrange, dim3(524288 / 256), dim3(256), 0, stream, x);

  hipFuncSetAttribute((const void*)gru_main,
                      hipFuncAttributeMaxDynamicSharedMemorySize, LDS_BYTES);
  hipLaunchKernelGGL(gru_main, dim3(NWG), dim3(256), LDS_BYTES, stream,
                     Wih0, Whh0, bih0, bhh0, Wih1, Whh1, bih1, bhh1, Wout,
                     bout, (float*)d_out);
}

// Round 9
// 6233.244 us; speedup vs baseline: 4.1411x; 4.1411x over previous
//
#include <hip/hip_runtime.h>

// ---------------------------------------------------------------------------
// Persistent 2-layer GRU + output Linear for MI355X (gfx950).
// B=32, T=1024, I=128, H=512, O=128.  ALL I/O FP32 (reference dtypes).
// Split-precision (hi+lo bf16) matmuls on the recurrent path. Fragment-layout
// write-once full-sequence rings (R12): consumer plain cached loads always
// coherent; producers write through to MALL at agent scope; publish only
// after vmcnt drain.
// Ledger: R14 hoist NEUTRAL; R15 64B-padded flags 7207->6310 (BEST);
// R16 arrival counters REGRESSED (publish must stay parallel stores);
// R17 merged L0+L1 REGRESSED (killed pipeline parallelism); R18 bug;
// R19 chain-overlap NEUTRAL; R20 XCD-local sc0 rings REGRESSED 4x (FETCH
// dropped 6x -- locality worked -- but sc0 spin/flag path far slower than
// MALL; L2-scope signaling is not a viable fast path on this part).
// R21 (this): EXACT R15 revert + ONE variable: flag stride 64B -> 256B
// (FSTR 16 -> 64). If MALL channel interleave is 256B-granular, each flag
// gets its own channel slot (R15 packed 4/stripe), further de-queueing the
// poll/publish storm. Worst case == R15 (banks best-known).
// Slot map: y0[idx] holds h0[t=idx-1] (idx0 = zeros); L0 step i reads y0[i],
// writes y0[i+1].  y1[idx] holds h1[t=idx-1]; L1 step i reads y0[i] (ih),
// y1[i-1] (hh), writes y1[i].  OUT step i reads y1[i-1] (t=i-2).
// ---------------------------------------------------------------------------

typedef __attribute__((ext_vector_type(8))) short short8;
typedef __attribute__((ext_vector_type(4))) float floatx4;

#define MFMA_BF16(a, b, c) __builtin_amdgcn_mfma_f32_16x16x32_bf16(a, b, c, 0, 0, 0)

#define NWG 130
#define FSTR 64                  // flag stride in uints (256B between flags)
#define EX_REC 132096            // rec-WG exchange byte offset (after weights)
#define EX_OUT 66560             // out-WG exchange byte offset (after Wout)
#define HBUF_REC (EX_REC + 24576)
#define LDS_BYTES 157696         // weights 132096 + ex 24576 + hbuf 1024
#define HID_OFF 4194304          // fp32-elem offset of hidden outputs in d_out
#define SLOT 32768               // ushorts per ring slot (hi 16K + lo 16K)

__device__ __align__(16) unsigned g_flags[16384];  // 130 flags, 256B apart
// full-sequence rings: 1025 slots x 32768 ushorts = 67 MB each
__device__ __align__(16) unsigned short g_y0[33587200];
__device__ __align__(16) unsigned short g_y1[33587200];
// x in fragment layout: [t][kb(4)][tile(2)][hi 64x8us | lo 64x8us]
__device__ __align__(16) unsigned short g_xf[8388608];

static __device__ __forceinline__ float bf2f(unsigned short u) {
  unsigned v = ((unsigned)u) << 16;
  return __builtin_bit_cast(float, v);
}
static __device__ __forceinline__ unsigned short f2bf(float f) {
  unsigned u = __builtin_bit_cast(unsigned, f);
  u = (u + 0x7fffu + ((u >> 16) & 1u)) >> 16;  // RNE
  return (unsigned short)u;
}
static __device__ __forceinline__ float sigf(float x) {
  return 1.f / (1.f + __expf(-x));
}
static __device__ __forceinline__ void st8(unsigned short* p, unsigned long long v) {
  __hip_atomic_store((unsigned long long*)p, v, __ATOMIC_RELAXED,
                     __HIP_MEMORY_SCOPE_AGENT);
}
static __device__ __forceinline__ unsigned long long pack4(const unsigned short* u) {
  return (unsigned long long)u[0] | ((unsigned long long)u[1] << 16) |
         ((unsigned long long)u[2] << 32) | ((unsigned long long)u[3] << 48);
}
// plain cached 16B fragment loads — slot addresses are write-once, so L2
// copies are always fresh (see header)
static __device__ __forceinline__ void ldfrag(const unsigned short* slot, int kb,
                                              int t, int lane, short8& hi,
                                              short8& lo) {
  const unsigned short* base = slot + (kb * 2 + t) * 1024 + lane * 8;
  hi = *(const short8*)base;
  lo = *(const short8*)(base + 512);
}

extern "C" __global__ void gru_init() {
  int i = blockIdx.x * blockDim.x + threadIdx.x;  // 49152 threads
  if (i < 16384) {
    g_flags[i] = 0u;
  } else if (i < 32768) {
    ((unsigned*)g_y0)[i - 16384] = 0u;   // y0 slot 0 = zeros (h0[-1])
  } else if (i < 49152) {
    ((unsigned*)g_y1)[i - 32768] = 0u;   // y1 slot 0 = zeros (h1[-1])
  }
}

extern "C" __global__ void x_arrange(const float* __restrict__ x) {
  int gid = blockIdx.x * 256 + threadIdx.x;  // 524288 total
  int t = gid >> 9;
  int rem = gid & 511;
  int kb = rem >> 7;
  int tile = (rem >> 6) & 1;
  int lane = rem & 63;
  int b = tile * 16 + (lane & 15);
  int k = kb * 32 + (lane >> 4) * 8;
  const float* src = x + b * 131072 + t * 128 + k;  // x is (B,T,I)
  short8 hi, lo;
#pragma unroll
  for (int e = 0; e < 8; ++e) {
    float v = src[e];
    unsigned short h = f2bf(v);
    hi[e] = (short)h;
    lo[e] = (short)f2bf(v - bf2f(h));
  }
  unsigned short* dst = g_xf + ((t * 4 + kb) * 2 + tile) * 1024;
  *(short8*)(dst + lane * 8) = hi;
  *(short8*)(dst + 512 + lane * 8) = lo;
}

// ---- recurrent layer step: 8 h-cols, hi/lo split MFMA (R12 body) ----
template <int LAYER>
__device__ __forceinline__ void layer_step(
    int i, int tid, int q, int lane, int jb,
    const unsigned short* whi, const unsigned short* wlo, float* ex, float* hbuf,
    float* __restrict__ dout,
    float bsr, float bsz, float bin, float bhn, float& hp) {
  constexpr int IHK = LAYER ? 512 : 128;
  constexpr int IHS = IHK / 32;        // ih k-blocks
  constexpr int KSW = LAYER ? 8 : 5;   // k-steps per wave
  constexpr int WSTR = IHK + 512 + 8;  // LDS weight row stride (elems)
  const int lm = lane & 15, lq = lane >> 4;

  const unsigned short* ihs = LAYER ? (g_y0 + (size_t)i * SLOT) : nullptr;
  const unsigned short* hhs =
      LAYER ? (g_y1 + (size_t)(i - 1) * SLOT) : (g_y0 + (size_t)i * SLOT);

  const floatx4 z4 = {0.f, 0.f, 0.f, 0.f};
  floatx4 t0h[2] = {z4, z4}, t0l[2] = {z4, z4};      // tile0 (r,z rows)
  floatx4 tih_h[2] = {z4, z4}, tih_l[2] = {z4, z4};  // tile1 n, ih part
  floatx4 thh_h[2] = {z4, z4}, thh_l[2] = {z4, z4};  // tile1 n, hh part

#pragma unroll
  for (int s = 0; s < KSW; ++s) {
    int ks = q * KSW + s;
    int colk = ks * 32 + lq * 8;
    short8 ah[2], al[2];
    if (ks < IHS) {
      if (LAYER == 0) {  // fragment-layout x, cached loads
        const unsigned short* xb = g_xf + (i * 4 + ks) * 2048;
        ah[0] = *(const short8*)(xb + lane * 8);
        al[0] = *(const short8*)(xb + 512 + lane * 8);
        ah[1] = *(const short8*)(xb + 1024 + lane * 8);
        al[1] = *(const short8*)(xb + 1536 + lane * 8);
      } else {
        ldfrag(ihs, ks, 0, lane, ah[0], al[0]);
        ldfrag(ihs, ks, 1, lane, ah[1], al[1]);
      }
    } else {
      ldfrag(hhs, ks - IHS, 0, lane, ah[0], al[0]);
      ldfrag(hhs, ks - IHS, 1, lane, ah[1], al[1]);
    }
    short8 b0h = *(const short8*)(whi + lm * WSTR + colk);
    short8 b0l = *(const short8*)(wlo + lm * WSTR + colk);
    short8 b1h = *(const short8*)(whi + (16 + lm) * WSTR + colk);
    short8 b1l = *(const short8*)(wlo + (16 + lm) * WSTR + colk);
#pragma unroll
    for (int t = 0; t < 2; ++t) {
      t0h[t] = MFMA_BF16(ah[t], b0h, t0h[t]);
      t0l[t] = MFMA_BF16(ah[t], b0l, t0l[t]);
      t0l[t] = MFMA_BF16(al[t], b0h, t0l[t]);
      if (ks < IHS) {
        tih_h[t] = MFMA_BF16(ah[t], b1h, tih_h[t]);
        tih_l[t] = MFMA_BF16(ah[t], b1l, tih_l[t]);
        tih_l[t] = MFMA_BF16(al[t], b1h, tih_l[t]);
      } else {
        thh_h[t] = MFMA_BF16(ah[t], b1h, thh_h[t]);
        thh_l[t] = MFMA_BF16(ah[t], b1l, thh_l[t]);
        thh_l[t] = MFMA_BF16(al[t], b1h, thh_l[t]);
      }
    }
  }
#pragma unroll
  for (int t = 0; t < 2; ++t) {
    *(floatx4*)(ex + ((0 * 4 + q) * 2 + t) * 256 + lane * 4) = t0h[t] + t0l[t];
    *(floatx4*)(ex + ((1 * 4 + q) * 2 + t) * 256 + lane * 4) = tih_h[t] + tih_l[t];
    *(floatx4*)(ex + ((2 * 4 + q) * 2 + t) * 256 + lane * 4) = thh_h[t] + thh_l[t];
  }
  __syncthreads();

  // elementwise: thread owns (batch m = tid>>3, col j = tid&7)
  int m = tid >> 3, j = tid & 7;
  int quad = (m >> 2) & 3, reg = m & 3, mh = m >> 4;
  int offr = (quad * 16 + j) * 4 + reg;      // r rows 0..7 in tile0
  int offz = (quad * 16 + 8 + j) * 4 + reg;  // z rows 8..15 in tile0
  float sr = 0, sz = 0, sih = 0, shh = 0;
#pragma unroll
  for (int qq = 0; qq < 4; ++qq) {
    const float* s0 = ex + ((0 * 4 + qq) * 2 + mh) * 256;
    const float* s1 = ex + ((1 * 4 + qq) * 2 + mh) * 256;
    const float* s2 = ex + ((2 * 4 + qq) * 2 + mh) * 256;
    sr += s0[offr];
    sz += s0[offz];
    sih += s1[offr];
    shh += s2[offr];
  }
  float r = sigf(sr + bsr);
  float z = sigf(sz + bsz);
  float n = tanhf(sih + bin + r * (shh + bhn));
  float h = (1.f - z) * n + z * hp;
  hp = h;
  hbuf[m * 8 + j] = h;
  if (i == (LAYER ? 1024 : 1023))  // final hidden state (plain store)
    dout[HID_OFF + LAYER * 16384 + m * 512 + jb + j] = h;
  __syncthreads();

  // 32 threads write this WG's 8 columns into the write-once ring slot
  // (agent-scope write-through: lands at MALL; consumers L2-fill from there)
  if (tid < 32) {
    int mm = tid;
    int t = mm >> 4;
    int lanep = (mm & 15) + 16 * ((jb >> 3) & 3);
    int kb = jb >> 5;
    unsigned short h4[8], l4[8];
#pragma unroll
    for (int e = 0; e < 8; ++e) {
      float v = hbuf[mm * 8 + e];
      unsigned short hh = f2bf(v);
      h4[e] = hh;
      l4[e] = f2bf(v - bf2f(hh));
    }
    unsigned short* slot =
        LAYER ? (g_y1 + (size_t)i * SLOT) : (g_y0 + (size_t)(i + 1) * SLOT);
    unsigned short* p = slot + (kb * 2 + t) * 1024 + lanep * 8;
    st8(p, pack4(h4));
    st8(p + 4, pack4(h4 + 4));
    st8(p + 512, pack4(l4));
    st8(p + 516, pack4(l4 + 4));
  }
}

__device__ __forceinline__ void out_step(
    int i, int tid, int lane, int q, int ob,
    const unsigned short* wl, float* ex,
    float* __restrict__ dout, const float* bo) {
  const int lm = lane & 15, lq = lane >> 4;
  const unsigned short* slot = g_y1 + (size_t)(i - 1) * SLOT;  // y1[t=i-2]
  const floatx4 z4 = {0.f, 0.f, 0.f, 0.f};
  floatx4 acc[4][2];
#pragma unroll
  for (int nt = 0; nt < 4; ++nt) { acc[nt][0] = z4; acc[nt][1] = z4; }
#pragma unroll
  for (int s = 0; s < 4; ++s) {
    int ks = q * 4 + s;
    int colk = ks * 32 + lq * 8;
    short8 a0 = *(const short8*)(slot + (ks * 2 + 0) * 1024 + lane * 8);
    short8 a1 = *(const short8*)(slot + (ks * 2 + 1) * 1024 + lane * 8);
#pragma unroll
    for (int nt = 0; nt < 4; ++nt) {
      short8 b = *(const short8*)(wl + (nt * 16 + lm) * 520 + colk);
      acc[nt][0] = MFMA_BF16(a0, b, acc[nt][0]);
      acc[nt][1] = MFMA_BF16(a1, b, acc[nt][1]);
    }
  }
#pragma unroll
  for (int nt = 0; nt < 4; ++nt) {
    *(floatx4*)(ex + ((q * 4 + nt) * 2 + 0) * 256 + lane * 4) = acc[nt][0];
    *(floatx4*)(ex + ((q * 4 + nt) * 2 + 1) * 256 + lane * 4) = acc[nt][1];
  }
  __syncthreads();
  int m = tid >> 3, oc = (tid & 7) * 8;
  int t_out = i - 2;
  float sv[8];
#pragma unroll
  for (int k = 0; k < 8; ++k) {
    int o = oc + k;
    int nt = o >> 4, jj = o & 15;
    int off = (((m >> 2) & 3) * 16 + jj) * 4 + (m & 3);
    int mh = m >> 4;
    float s = bo[k];
#pragma unroll
    for (int qq = 0; qq < 4; ++qq) s += ex[((qq * 4 + nt) * 2 + mh) * 256 + off];
    sv[k] = s;
  }
  float* dst = dout + m * 131072 + t_out * 128 + ob + oc;  // (B,T,O) fp32
  *(floatx4*)dst = floatx4{sv[0], sv[1], sv[2], sv[3]};
  *(floatx4*)(dst + 4) = floatx4{sv[4], sv[5], sv[6], sv[7]};
}

extern "C" __global__ void __launch_bounds__(256, 1) gru_main(
    const float* __restrict__ Wih0, const float* __restrict__ Whh0,
    const float* __restrict__ bih0, const float* __restrict__ bhh0,
    const float* __restrict__ Wih1, const float* __restrict__ Whh1,
    const float* __restrict__ bih1, const float* __restrict__ bhh1,
    const float* __restrict__ Wout, const float* __restrict__ boutp,
    float* __restrict__ dout) {
  extern __shared__ char smem[];
  __shared__ int sbail;

  unsigned* flags = g_flags;

  const int w = blockIdx.x;
  const int tid = threadIdx.x;
  const int lane = tid & 63;
  const int q = tid >> 6;
  const int role = (w < 128) ? ((w < 64) ? 0 : 1) : 2;

  if (tid == 0) sbail = 0;

  unsigned short* whi = (unsigned short*)smem;
  float* ex = (float*)(smem + (role == 2 ? EX_OUT : EX_REC));
  float* hbuf = (float*)(smem + HBUF_REC);
  {
    int exn = (role == 2) ? 8192 : 6144;
    for (int idx = tid; idx < exn; idx += 256) ex[idx] = 0.f;
  }

  float bsr = 0, bsz = 0, bin = 0, bhn = 0;
  float bo[8] = {0, 0, 0, 0, 0, 0, 0, 0};
  int jb = 0, ob = 0;
  const unsigned short* wlo = nullptr;

  if (role < 2) {
    jb = (role == 0 ? w : w - 64) * 8;
    const int IHK = role ? 512 : 128;
    const int KTOT = IHK + 512;
    const int WSTR = KTOT + 8;
    unsigned short* wlo_w = whi + 32 * WSTR;
    wlo = wlo_w;
    const float* Wih = role ? Wih1 : Wih0;
    const float* Whh = role ? Whh1 : Whh0;
    const float* bih = role ? bih1 : bih0;
    const float* bhh = role ? bhh1 : bhh0;
    int cpr = KTOT / 8;
    for (int idx = tid; idx < 32 * cpr; idx += 256) {
      int r = idx / cpr, c = idx - r * cpr;
      int k0 = c * 8;
      short8 hi8 = {0, 0, 0, 0, 0, 0, 0, 0}, lo8 = {0, 0, 0, 0, 0, 0, 0, 0};
      if (r < 24) {  // rows 24..31 zero pad
        int gate = r >> 3, jl = r & 7;
        int grow = gate * 512 + jb + jl;
        const float* src = (k0 < IHK) ? (Wih + grow * IHK + k0)
                                      : (Whh + grow * 512 + (k0 - IHK));
#pragma unroll
        for (int e = 0; e < 8; ++e) {
          float v = src[e];
          unsigned short h16 = f2bf(v);
          hi8[e] = (short)h16;
          lo8[e] = (short)f2bf(v - bf2f(h16));
        }
      }
      *(short8*)(whi + r * WSTR + k0) = hi8;
      *(short8*)(wlo_w + r * WSTR + k0) = lo8;
    }
    for (int idx = tid; idx < 32 * 8; idx += 256) {
      int r = idx >> 3, kk = KTOT + (idx & 7);
      whi[r * WSTR + kk] = 0;
      wlo_w[r * WSTR + kk] = 0;
    }
    int g0 = jb + (tid & 7);
    bsr = bih[g0] + bhh[g0];
    bsz = bih[512 + g0] + bhh[512 + g0];
    bin = bih[1024 + g0];
    bhn = bhh[1024 + g0];
  } else {
    ob = (w - 128) * 64;
    for (int idx = tid; idx < 64 * 64; idx += 256) {
      int r = idx >> 6, c = idx & 63;
      const float* src = Wout + (ob + r) * 512 + c * 8;
      short8 hi8;
#pragma unroll
      for (int e = 0; e < 8; ++e) hi8[e] = (short)f2bf(src[e]);
      *(short8*)(whi + r * 520 + c * 8) = hi8;
    }
    for (int idx = tid; idx < 64 * 8; idx += 256)
      whi[(idx >> 3) * 520 + 512 + (idx & 7)] = 0;
#pragma unroll
    for (int k = 0; k < 8; ++k) bo[k] = boutp[ob + (tid & 7) * 8 + k];
  }
  // one-time tag invalidate: clears any prior-launch ring lines from L1/L2
  __builtin_amdgcn_fence(__ATOMIC_ACQUIRE, "agent");
  __syncthreads();

  float hp = 0.f;

  for (int i = 0; i < 1026; ++i) {
    // ---- single-wave ballot poll (true deps only; no anti-deps) ----
    // Flags padded to 256B apart: poll/publish storm spread across ~130
    // distinct MALL channel slots (R15's 64B stride packed 4 per 256B
    // stripe). Protocol otherwise identical to R15.
    if (i > 0 && tid < 64) {
      int guard = 0;
      for (;;) {
        bool ok;
        if (role == 0) {         // all L0 peers finished step i-1
          ok = __hip_atomic_load(flags + tid * FSTR, __ATOMIC_RELAXED,
                                 __HIP_MEMORY_SCOPE_AGENT) >= (unsigned)i;
        } else if (role == 1) {  // all L0 and L1 peers finished step i-1
          ok = (__hip_atomic_load(flags + tid * FSTR, __ATOMIC_RELAXED,
                                  __HIP_MEMORY_SCOPE_AGENT) >= (unsigned)i) &&
               (__hip_atomic_load(flags + (64 + tid) * FSTR, __ATOMIC_RELAXED,
                                  __HIP_MEMORY_SCOPE_AGENT) >= (unsigned)i);
        } else {                 // OUT: all L1 finished step i-1
          ok = __hip_atomic_load(flags + (64 + tid) * FSTR, __ATOMIC_RELAXED,
                                 __HIP_MEMORY_SCOPE_AGENT) >= (unsigned)i;
        }
        if (__ballot(ok) == ~0ull) break;
        __builtin_amdgcn_s_sleep(1);
        if (++guard > (1 << 17)) { sbail = 1; break; }
      }
    }
    __syncthreads();
    if (sbail) break;

    bool active = (role == 0) ? (i < 1024)
                : (role == 1) ? (i >= 1 && i < 1025)
                              : (i >= 2);
    if (active) {
      if (role == 0) {
        layer_step<0>(i, tid, q, lane, jb, whi, wlo, ex, hbuf, dout,
                      bsr, bsz, bin, bhn, hp);
      } else if (role == 1) {
        layer_step<1>(i, tid, q, lane, jb, whi, wlo, ex, hbuf, dout,
                      bsr, bsz, bin, bhn, hp);
      } else {
        out_step(i, tid, lane, q, ob, whi, ex, dout, bo);
      }
    }
    // ---- publish: barrier drains vmcnt (ring stores at MALL), then flag ----
    __syncthreads();
    if (tid == 0)
      __hip_atomic_store(&flags[w * FSTR], (unsigned)(i + 1), __ATOMIC_RELAXED,
                         __HIP_MEMORY_SCOPE_AGENT);
  }
}

extern "C" void kernel_launch(void* const* d_in, const int* in_sizes, int n_in,
                              void* d_out, int out_size, void* d_ws, size_t ws_size,
                              hipStream_t stream) {
  const float* x = (const float*)d_in[0];
  const float* Wih0 = (const float*)d_in[1];
  const float* Whh0 = (const float*)d_in[2];
  const float* bih0 = (const float*)d_in[3];
  const float* bhh0 = (const float*)d_in[4];
  const float* Wih1 = (const float*)d_in[5];
  const float* Whh1 = (const float*)d_in[6];
  const float* bih1 = (const float*)d_in[7];
  const float* bhh1 = (const float*)d_in[8];
  const float* Wout = (const float*)d_in[9];
  const float* bout = (const float*)d_in[10];

  hipLaunchKernelGGL(gru_init, dim3(192), dim3(256), 0, stream);
  hipLaunchKernelGGL(x_arrange, dim3(524288 / 256), dim3(256), 0, stream, x);

  hipFuncSetAttribute((const void*)gru_main,
                      hipFuncAttributeMaxDynamicSharedMemorySize, LDS_BYTES);
  hipLaunchKernelGGL(gru_main, dim3(NWG), dim3(256), LDS_BYTES, stream,
                     Wih0, Whh0, bih0, bhh0, Wih1, Whh1, bih1, bhh1, Wout,
                     bout, (float*)d_out);
}